// Round 19
// baseline (94.479 us; speedup 1.0000x reference)
//
#include <hip/hip_runtime.h>

#define BLOCK 512   // 8 waves
#define GRID  768   // 3 blocks/CU iff VGPR<=64 (setprio-fence diet); LDS 53760*3 fits

typedef __attribute__((ext_vector_type(8))) short short8;   // 8 x bf16
typedef __attribute__((ext_vector_type(4))) float f32x4;    // MFMA C/D frag

#define TWOLOG2E  2.8853900817779268f
#define NLOG2E   -1.4426950408889634f
#define HP 72   // 144B pitch: 16B-aligned (R12); b128 reads 2-way = free

__device__ __forceinline__ unsigned short f2bf(float f) {
    unsigned u = __builtin_bit_cast(unsigned, f);
    u += 0x7FFFu + ((u >> 16) & 1u);
    return (unsigned short)(u >> 16);
}

__device__ __forceinline__ unsigned pkbf(float lo, float hi) {
    unsigned r;
    asm("v_cvt_pk_bf16_f32 %0, %1, %2" : "=v"(r) : "v"(lo), "v"(hi));
    return r;
}

__device__ __forceinline__ float tanh_z(float z) {
    float e = __builtin_amdgcn_exp2f(z);
    return fmaf(-2.0f, __builtin_amdgcn_rcpf(1.0f + e), 1.0f);
}

// LN+tanh; bias already in acc via MFMA C-init (stats-only prologue)
#define LN_T(PG, PT, A)                                                       \
    {                                                                         \
        float s_ = 0.f, q_ = 0.f;                                             \
        _Pragma("unroll")                                                     \
        for (int m = 0; m < 4; ++m) {                                         \
            s_ += (A[m][0] + A[m][1]) + (A[m][2] + A[m][3]);                  \
            q_ = fmaf(A[m][0], A[m][0], q_); q_ = fmaf(A[m][1], A[m][1], q_); \
            q_ = fmaf(A[m][2], A[m][2], q_); q_ = fmaf(A[m][3], A[m][3], q_); \
        }                                                                     \
        s_ += __shfl_xor(s_, 16); s_ += __shfl_xor(s_, 32);                   \
        q_ += __shfl_xor(q_, 16); q_ += __shfl_xor(q_, 32);                   \
        const float mu = s_ * 0.015625f;                                      \
        float var = fmaf(q_, 0.015625f, -mu * mu);                            \
        var = fmaxf(var, 0.0f);                                               \
        const float rs = __builtin_amdgcn_rsqf(var + 1e-5f);                  \
        const float mrs = mu * rs;                                            \
        _Pragma("unroll")                                                     \
        for (int m = 0; m < 4; ++m) {                                         \
            const float4 pg = *reinterpret_cast<const float4*>(               \
                plds + (PG) * 64 + m * 16 + kg4);                             \
            const float4 pt = *reinterpret_cast<const float4*>(               \
                plds + (PT) * 64 + m * 16 + kg4);                             \
            A[m][0] = tanh_z(fmaf(fmaf(A[m][0], rs, -mrs), pg.x, pt.x));      \
            A[m][1] = tanh_z(fmaf(fmaf(A[m][1], rs, -mrs), pg.y, pt.y));      \
            A[m][2] = tanh_z(fmaf(fmaf(A[m][2], rs, -mrs), pg.z, pt.z));      \
            A[m][3] = tanh_z(fmaf(fmaf(A[m][3], rs, -mrs), pg.w, pt.w));      \
        }                                                                     \
    }

#define H_STORE(A)                                                            \
    _Pragma("unroll")                                                         \
    for (int m = 0; m < 4; ++m) {                                             \
        uint2 u2;                                                             \
        u2.x = pkbf(A[m][0], A[m][1]);                                        \
        u2.y = pkbf(A[m][2], A[m][3]);                                        \
        *reinterpret_cast<uint2*>(hwv + cl * HP + m * 16 + kg4) = u2;         \
    }

#define ACC_INIT(ACC, PB)                                                     \
    _Pragma("unroll")                                                         \
    for (int m = 0; m < 4; ++m)                                               \
        ACC[m] = __builtin_bit_cast(f32x4, *reinterpret_cast<const float4*>(  \
            plds + (PB) * 64 + m * 16 + kg4));

#define L1_KB(AF, ACC, KB)                                                    \
    _Pragma("unroll")                                                         \
    for (int m = 0; m < 4; ++m) {                                             \
        const short8 wf = *reinterpret_cast<const short8*>(                   \
            &wlds[(m * 4 + (KB)) * 512 + lane * 8]);                          \
        ACC[m] = __builtin_amdgcn_mfma_f32_16x16x32_bf16(wf, AF, ACC[m], 0, 0, 0); \
    }

// setprio(1..0) around the MFMA cluster: CU arbitration + scheduling fence
// (R18: fence effect alone cut VGPR 100->52 on the dual body)
#define L23_MFMA(ACC, BASE)                                                   \
    __builtin_amdgcn_s_setprio(1);                                            \
    _Pragma("unroll")                                                         \
    for (int kb = 0; kb < 2; ++kb) {                                          \
        const short8 hf = *reinterpret_cast<const short8*>(                   \
            hwv + cl * HP + kb * 32 + kg * 8);                                \
        _Pragma("unroll")                                                     \
        for (int m = 0; m < 4; ++m) {                                         \
            const short8 wf = *reinterpret_cast<const short8*>(               \
                &wlds[((BASE) + m * 2 + kb) * 512 + lane * 8]);               \
            ACC[m] = __builtin_amdgcn_mfma_f32_16x16x32_bf16(wf, hf, ACC[m], 0, 0, 0); \
        }                                                                     \
    }                                                                         \
    __builtin_amdgcn_s_setprio(0);

#define LDIDX(T, A_, B_)                                                      \
    {                                                                         \
        const int tc_ = min((T), ntiles - 1);                                 \
        const int er_ = min((tc_ << 4) + cl, E - 1);                          \
        A_ = ei[er_]; B_ = ei[E + er_];                                       \
    }

template<bool PREBF>
__global__ __launch_bounds__(BLOCK) void edge_mlp_t(
    const void* __restrict__ xsrc, const int* __restrict__ ei,
    const float* __restrict__ W1, const float* __restrict__ b1,
    const float* __restrict__ g1, const float* __restrict__ bt1,
    const float* __restrict__ W2, const float* __restrict__ b2,
    const float* __restrict__ g2, const float* __restrict__ bt2,
    const float* __restrict__ W3, const float* __restrict__ b3,
    const float* __restrict__ g3, const float* __restrict__ bt3,
    const float* __restrict__ W4, const float* __restrict__ b4,
    float* __restrict__ out, int E)
{
    __shared__ unsigned short wlds[32 * 512];        // 32 KiB W^T frags
    __shared__ unsigned short hlds[8 * 16 * HP];     // 18 KiB per-wave h tiles
    __shared__ float plds[10 * 64];                  // 2.5 KiB params

    const int tid  = threadIdx.x;
    const int widx = tid >> 6;
    const int lane = tid & 63;
    const int kg   = lane >> 4;
    const int cl   = lane & 15;
    const int kg4  = kg * 4;

    for (int fi = widx; fi < 32; fi += 8) {
        const float* Wsrc; int m, kb;
        if (fi < 16) { Wsrc = W1; m = fi >> 2; kb = fi & 3; }
        else { int f = fi - 16; Wsrc = (f < 8) ? W2 : W3; f &= 7; m = f >> 1; kb = f & 1; }
        const float* src = Wsrc + (kb * 32 + kg * 8) * 64 + m * 16 + cl;
        short8 pk8;
        #pragma unroll
        for (int j = 0; j < 8; ++j) pk8[j] = (short)f2bf(src[j * 64]);
        *reinterpret_cast<short8*>(&wlds[fi * 512 + lane * 8]) = pk8;
    }
    for (int i = tid; i < 640; i += BLOCK) {
        const int p = i >> 6, c = i & 63;
        const float* sp; float sc;
        switch (p) {
            case 0: sp = b1;  sc = 1.0f;     break;
            case 1: sp = g1;  sc = TWOLOG2E; break;
            case 2: sp = bt1; sc = TWOLOG2E; break;
            case 3: sp = b2;  sc = 1.0f;     break;
            case 4: sp = g2;  sc = TWOLOG2E; break;
            case 5: sp = bt2; sc = TWOLOG2E; break;
            case 6: sp = b3;  sc = 1.0f;     break;
            case 7: sp = g3;  sc = TWOLOG2E; break;
            case 8: sp = bt3; sc = TWOLOG2E; break;
            default: sp = W4; sc = NLOG2E;   break;
        }
        plds[i] = sp[c] * sc;
    }
    const float b4s = b4[0] * NLOG2E;
    __syncthreads();

    const unsigned short* xb = (const unsigned short*)xsrc;
    const float*          xf = (const float*)xsrc;
    unsigned short* hwv = hlds + widx * (16 * HP);

    const int ntiles = (E + 15) >> 4;
    const int NW = (int)gridDim.x * 8;

    int t = (int)blockIdx.x * 8 + widx;
    int ns, ne;
    LDIDX(t, ns, ne);

    for (; t < ntiles; t += NW) {
        int nns, nne;
        LDIDX(t + NW, nns, nne);

        f32x4 acc[4];
        ACC_INIT(acc, 0);

        if constexpr (PREBF) {
            short8 xa[4];
            #pragma unroll
            for (int kb = 0; kb < 4; ++kb) {
                const unsigned off = (unsigned)(kb < 2 ? ns : ne) * 64u
                                   + (unsigned)((kb & 1) * 32 + kg * 8);
                xa[kb] = *reinterpret_cast<const short8*>(xb + off);
            }
            __builtin_amdgcn_s_setprio(1);
            #pragma unroll
            for (int kb = 0; kb < 4; ++kb) { L1_KB(xa[kb], acc, kb); }
            __builtin_amdgcn_s_setprio(0);
        } else {
            // issue all 8 f32 loads, then per-kb convert+MFMA (fenced cluster)
            float4 u[8];
            #pragma unroll
            for (int kb = 0; kb < 4; ++kb) {
                const unsigned off = (unsigned)(kb < 2 ? ns : ne) * 64u
                                   + (unsigned)((kb & 1) * 32 + kg * 8);
                u[2 * kb]     = *reinterpret_cast<const float4*>(xf + off);
                u[2 * kb + 1] = *reinterpret_cast<const float4*>(xf + off + 4);
            }
            __builtin_amdgcn_s_setprio(1);
            #pragma unroll
            for (int kb = 0; kb < 4; ++kb) {
                uint4 tp_;
                tp_.x = pkbf(u[2 * kb].x,     u[2 * kb].y);
                tp_.y = pkbf(u[2 * kb].z,     u[2 * kb].w);
                tp_.z = pkbf(u[2 * kb + 1].x, u[2 * kb + 1].y);
                tp_.w = pkbf(u[2 * kb + 1].z, u[2 * kb + 1].w);
                const short8 af = __builtin_bit_cast(short8, tp_);
                L1_KB(af, acc, kb);
            }
            __builtin_amdgcn_s_setprio(0);
        }
        ns = nns; ne = nne;

        LN_T(1, 2, acc);
        H_STORE(acc);

        // ---------- Layer 2 ----------
        f32x4 acc2[4];
        ACC_INIT(acc2, 3);
        L23_MFMA(acc2, 16);
        LN_T(4, 5, acc2);
        H_STORE(acc2);

        // ---------- Layer 3 ----------
        f32x4 acc3[4];
        ACC_INIT(acc3, 6);
        L23_MFMA(acc3, 24);
        LN_T(7, 8, acc3);

        // ---------- Layer 4 ----------
        float p = 0.f;
        #pragma unroll
        for (int m = 0; m < 4; ++m) {
            const float4 w4 = *reinterpret_cast<const float4*>(
                plds + 9 * 64 + m * 16 + kg4);
            p = fmaf(acc3[m][0], w4.x, p); p = fmaf(acc3[m][1], w4.y, p);
            p = fmaf(acc3[m][2], w4.z, p); p = fmaf(acc3[m][3], w4.w, p);
        }
        p += __shfl_xor(p, 16); p += __shfl_xor(p, 32);
        if (kg == 0) {
            const int e = (t << 4) + cl;
            if (e < E) {
                out[e] = __builtin_amdgcn_rcpf(
                    1.0f + __builtin_amdgcn_exp2f(p + b4s));
            }
        }
    }
}

__global__ __launch_bounds__(256) void cvt_x_bf16(const float* __restrict__ x,
                                                  unsigned short* __restrict__ xbf,
                                                  int n) {
    const int i = (blockIdx.x * 256 + threadIdx.x) * 8;
    if (i >= n) return;
    const float4 u0 = *reinterpret_cast<const float4*>(x + i);
    const float4 u1 = *reinterpret_cast<const float4*>(x + i + 4);
    uint4 t;
    t.x = pkbf(u0.x, u0.y); t.y = pkbf(u0.z, u0.w);
    t.z = pkbf(u1.x, u1.y); t.w = pkbf(u1.z, u1.w);
    *reinterpret_cast<uint4*>(xbf + i) = t;
}

extern "C" void kernel_launch(void* const* d_in, const int* in_sizes, int n_in,
                              void* d_out, int out_size, void* d_ws, size_t ws_size,
                              hipStream_t stream) {
    const float* x   = (const float*)d_in[0];
    const int*   ei  = (const int*)  d_in[1];
    const float* W1  = (const float*)d_in[2];
    const float* b1  = (const float*)d_in[3];
    const float* g1  = (const float*)d_in[4];
    const float* bt1 = (const float*)d_in[5];
    const float* W2  = (const float*)d_in[6];
    const float* b2  = (const float*)d_in[7];
    const float* g2  = (const float*)d_in[8];
    const float* bt2 = (const float*)d_in[9];
    const float* W3  = (const float*)d_in[10];
    const float* b3  = (const float*)d_in[11];
    const float* g3  = (const float*)d_in[12];
    const float* bt3 = (const float*)d_in[13];
    const float* W4  = (const float*)d_in[14];
    const float* b4  = (const float*)d_in[15];
    float* out = (float*)d_out;

    const int E  = in_sizes[1] / 2;
    const int nX = in_sizes[0];

    const bool prebf = (ws_size >= (size_t)nX * 2);

    if (prebf) {
        unsigned short* xbf = (unsigned short*)d_ws;
        const int grid_c = (nX / 8 + 255) / 256;
        hipLaunchKernelGGL(cvt_x_bf16, dim3(grid_c), dim3(256), 0, stream, x, xbf, nX);
        hipLaunchKernelGGL((edge_mlp_t<true>), dim3(GRID), dim3(BLOCK), 0, stream,
                           (const void*)xbf, ei, W1, b1, g1, bt1, W2, b2, g2, bt2,
                           W3, b3, g3, bt3, W4, b4, out, E);
    } else {
        hipLaunchKernelGGL((edge_mlp_t<false>), dim3(GRID), dim3(BLOCK), 0, stream,
                           (const void*)x, ei, W1, b1, g1, bt1, W2, b2, g2, bt2,
                           W3, b3, g3, bt3, W4, b4, out, E);
    }
}

// Round 20
// 93.642 us; speedup vs baseline: 1.0089x; 1.0089x over previous
//
#include <hip/hip_runtime.h>

#define BLOCK 512   // 8 waves
#define GRID  768   // 3 blocks/CU (R19-verified: VGPR 40, LDS 53760*3 fits)

typedef __attribute__((ext_vector_type(8))) short short8;   // 8 x bf16
typedef __attribute__((ext_vector_type(4))) float f32x4;    // MFMA C/D frag
typedef __attribute__((ext_vector_type(2))) float f32x2;    // v_pk_* f32 pair

#define TWOLOG2E  2.8853900817779268f
#define NLOG2E   -1.4426950408889634f
#define HP 72   // 144B pitch: 16B-aligned (R12); b128 reads 2-way = free

__device__ __forceinline__ unsigned short f2bf(float f) {
    unsigned u = __builtin_bit_cast(unsigned, f);
    u += 0x7FFFu + ((u >> 16) & 1u);
    return (unsigned short)(u >> 16);
}

__device__ __forceinline__ unsigned pkbf(float lo, float hi) {
    unsigned r;
    asm("v_cvt_pk_bf16_f32 %0, %1, %2" : "=v"(r) : "v"(lo), "v"(hi));
    return r;
}

__device__ __forceinline__ float tanh_z(float z) {
    float e = __builtin_amdgcn_exp2f(z);
    return fmaf(-2.0f, __builtin_amdgcn_rcpf(1.0f + e), 1.0f);
}

// LN+tanh; bias pre-added via MFMA C-init. Stats + affine on f32x2 pairs so
// the backend can emit v_pk_add_f32 / v_pk_fma_f32 (VOP3P, full-rate on gfx950).
#define LN_T(PG, PT, A)                                                       \
    {                                                                         \
        f32x2 s2 = {0.f, 0.f}, q2 = {0.f, 0.f};                               \
        _Pragma("unroll")                                                     \
        for (int m = 0; m < 4; ++m) {                                         \
            const f32x2 lo = {A[m][0], A[m][1]};                              \
            const f32x2 hi = {A[m][2], A[m][3]};                              \
            s2 += lo + hi;                                                    \
            q2 = __builtin_elementwise_fma(lo, lo, q2);                       \
            q2 = __builtin_elementwise_fma(hi, hi, q2);                       \
        }                                                                     \
        float s_ = s2.x + s2.y, q_ = q2.x + q2.y;                             \
        s_ += __shfl_xor(s_, 16); s_ += __shfl_xor(s_, 32);                   \
        q_ += __shfl_xor(q_, 16); q_ += __shfl_xor(q_, 32);                   \
        const float mu = s_ * 0.015625f;                                      \
        float var = fmaf(q_, 0.015625f, -mu * mu);                            \
        var = fmaxf(var, 0.0f);                                               \
        const float rs = __builtin_amdgcn_rsqf(var + 1e-5f);                  \
        const float mrs = mu * rs;                                            \
        const f32x2 rs2 = {rs, rs};                                           \
        const f32x2 nm2 = {-mrs, -mrs};                                       \
        _Pragma("unroll")                                                     \
        for (int m = 0; m < 4; ++m) {                                         \
            const float4 pg = *reinterpret_cast<const float4*>(               \
                plds + (PG) * 64 + m * 16 + kg4);                             \
            const float4 pt = *reinterpret_cast<const float4*>(               \
                plds + (PT) * 64 + m * 16 + kg4);                             \
            f32x2 lo = {A[m][0], A[m][1]};                                    \
            f32x2 hi = {A[m][2], A[m][3]};                                    \
            lo = __builtin_elementwise_fma(lo, rs2, nm2);                     \
            hi = __builtin_elementwise_fma(hi, rs2, nm2);                     \
            const f32x2 glo = {pg.x, pg.y}, ghi = {pg.z, pg.w};               \
            const f32x2 tlo = {pt.x, pt.y}, thi = {pt.z, pt.w};               \
            lo = __builtin_elementwise_fma(lo, glo, tlo);                     \
            hi = __builtin_elementwise_fma(hi, ghi, thi);                     \
            A[m][0] = tanh_z(lo.x); A[m][1] = tanh_z(lo.y);                   \
            A[m][2] = tanh_z(hi.x); A[m][3] = tanh_z(hi.y);                   \
        }                                                                     \
    }

#define H_STORE(A)                                                            \
    _Pragma("unroll")                                                         \
    for (int m = 0; m < 4; ++m) {                                             \
        uint2 u2;                                                             \
        u2.x = pkbf(A[m][0], A[m][1]);                                        \
        u2.y = pkbf(A[m][2], A[m][3]);                                        \
        *reinterpret_cast<uint2*>(hwv + cl * HP + m * 16 + kg4) = u2;         \
    }

#define ACC_INIT(ACC, PB)                                                     \
    _Pragma("unroll")                                                         \
    for (int m = 0; m < 4; ++m)                                               \
        ACC[m] = __builtin_bit_cast(f32x4, *reinterpret_cast<const float4*>(  \
            plds + (PB) * 64 + m * 16 + kg4));

#define L1_KB(AF, ACC, KB)                                                    \
    _Pragma("unroll")                                                         \
    for (int m = 0; m < 4; ++m) {                                             \
        const short8 wf = *reinterpret_cast<const short8*>(                   \
            &wlds[(m * 4 + (KB)) * 512 + lane * 8]);                          \
        ACC[m] = __builtin_amdgcn_mfma_f32_16x16x32_bf16(wf, AF, ACC[m], 0, 0, 0); \
    }

// setprio fence around MFMA clusters (R18/R19: arbitration + live-range control)
#define L23_MFMA(ACC, BASE)                                                   \
    __builtin_amdgcn_s_setprio(1);                                            \
    _Pragma("unroll")                                                         \
    for (int kb = 0; kb < 2; ++kb) {                                          \
        const short8 hf = *reinterpret_cast<const short8*>(                   \
            hwv + cl * HP + kb * 32 + kg * 8);                                \
        _Pragma("unroll")                                                     \
        for (int m = 0; m < 4; ++m) {                                         \
            const short8 wf = *reinterpret_cast<const short8*>(               \
                &wlds[((BASE) + m * 2 + kb) * 512 + lane * 8]);               \
            ACC[m] = __builtin_amdgcn_mfma_f32_16x16x32_bf16(wf, hf, ACC[m], 0, 0, 0); \
        }                                                                     \
    }                                                                         \
    __builtin_amdgcn_s_setprio(0);

#define LDIDX(T, A_, B_)                                                      \
    {                                                                         \
        const int tc_ = min((T), ntiles - 1);                                 \
        const int er_ = min((tc_ << 4) + cl, E - 1);                          \
        A_ = ei[er_]; B_ = ei[E + er_];                                       \
    }

template<bool PREBF>
__global__ __launch_bounds__(BLOCK) void edge_mlp_t(
    const void* __restrict__ xsrc, const int* __restrict__ ei,
    const float* __restrict__ W1, const float* __restrict__ b1,
    const float* __restrict__ g1, const float* __restrict__ bt1,
    const float* __restrict__ W2, const float* __restrict__ b2,
    const float* __restrict__ g2, const float* __restrict__ bt2,
    const float* __restrict__ W3, const float* __restrict__ b3,
    const float* __restrict__ g3, const float* __restrict__ bt3,
    const float* __restrict__ W4, const float* __restrict__ b4,
    float* __restrict__ out, int E)
{
    __shared__ unsigned short wlds[32 * 512];        // 32 KiB W^T frags
    __shared__ unsigned short hlds[8 * 16 * HP];     // 18 KiB per-wave h tiles
    __shared__ float plds[10 * 64];                  // 2.5 KiB params

    const int tid  = threadIdx.x;
    const int widx = tid >> 6;
    const int lane = tid & 63;
    const int kg   = lane >> 4;
    const int cl   = lane & 15;
    const int kg4  = kg * 4;

    for (int fi = widx; fi < 32; fi += 8) {
        const float* Wsrc; int m, kb;
        if (fi < 16) { Wsrc = W1; m = fi >> 2; kb = fi & 3; }
        else { int f = fi - 16; Wsrc = (f < 8) ? W2 : W3; f &= 7; m = f >> 1; kb = f & 1; }
        const float* src = Wsrc + (kb * 32 + kg * 8) * 64 + m * 16 + cl;
        short8 pk8;
        #pragma unroll
        for (int j = 0; j < 8; ++j) pk8[j] = (short)f2bf(src[j * 64]);
        *reinterpret_cast<short8*>(&wlds[fi * 512 + lane * 8]) = pk8;
    }
    for (int i = tid; i < 640; i += BLOCK) {
        const int p = i >> 6, c = i & 63;
        const float* sp; float sc;
        switch (p) {
            case 0: sp = b1;  sc = 1.0f;     break;
            case 1: sp = g1;  sc = TWOLOG2E; break;
            case 2: sp = bt1; sc = TWOLOG2E; break;
            case 3: sp = b2;  sc = 1.0f;     break;
            case 4: sp = g2;  sc = TWOLOG2E; break;
            case 5: sp = bt2; sc = TWOLOG2E; break;
            case 6: sp = b3;  sc = 1.0f;     break;
            case 7: sp = g3;  sc = TWOLOG2E; break;
            case 8: sp = bt3; sc = TWOLOG2E; break;
            default: sp = W4; sc = NLOG2E;   break;
        }
        plds[i] = sp[c] * sc;
    }
    const float b4s = b4[0] * NLOG2E;
    __syncthreads();

    const unsigned short* xb = (const unsigned short*)xsrc;
    const float*          xf = (const float*)xsrc;
    unsigned short* hwv = hlds + widx * (16 * HP);

    const int ntiles = (E + 15) >> 4;
    const int NW = (int)gridDim.x * 8;

    int t = (int)blockIdx.x * 8 + widx;
    int ns, ne;
    LDIDX(t, ns, ne);

    for (; t < ntiles; t += NW) {
        int nns, nne;
        LDIDX(t + NW, nns, nne);

        f32x4 acc[4];
        ACC_INIT(acc, 0);

        if constexpr (PREBF) {
            short8 xa[4];
            #pragma unroll
            for (int kb = 0; kb < 4; ++kb) {
                const unsigned off = (unsigned)(kb < 2 ? ns : ne) * 64u
                                   + (unsigned)((kb & 1) * 32 + kg * 8);
                xa[kb] = *reinterpret_cast<const short8*>(xb + off);
            }
            __builtin_amdgcn_s_setprio(1);
            #pragma unroll
            for (int kb = 0; kb < 4; ++kb) { L1_KB(xa[kb], acc, kb); }
            __builtin_amdgcn_s_setprio(0);
        } else {
            float4 u[8];
            #pragma unroll
            for (int kb = 0; kb < 4; ++kb) {
                const unsigned off = (unsigned)(kb < 2 ? ns : ne) * 64u
                                   + (unsigned)((kb & 1) * 32 + kg * 8);
                u[2 * kb]     = *reinterpret_cast<const float4*>(xf + off);
                u[2 * kb + 1] = *reinterpret_cast<const float4*>(xf + off + 4);
            }
            __builtin_amdgcn_s_setprio(1);
            #pragma unroll
            for (int kb = 0; kb < 4; ++kb) {
                uint4 tp_;
                tp_.x = pkbf(u[2 * kb].x,     u[2 * kb].y);
                tp_.y = pkbf(u[2 * kb].z,     u[2 * kb].w);
                tp_.z = pkbf(u[2 * kb + 1].x, u[2 * kb + 1].y);
                tp_.w = pkbf(u[2 * kb + 1].z, u[2 * kb + 1].w);
                const short8 af = __builtin_bit_cast(short8, tp_);
                L1_KB(af, acc, kb);
            }
            __builtin_amdgcn_s_setprio(0);
        }
        ns = nns; ne = nne;

        LN_T(1, 2, acc);
        H_STORE(acc);

        // ---------- Layer 2 ----------
        f32x4 acc2[4];
        ACC_INIT(acc2, 3);
        L23_MFMA(acc2, 16);
        LN_T(4, 5, acc2);
        H_STORE(acc2);

        // ---------- Layer 3 ----------
        f32x4 acc3[4];
        ACC_INIT(acc3, 6);
        L23_MFMA(acc3, 24);
        LN_T(7, 8, acc3);

        // ---------- Layer 4: packed dot ----------
        f32x2 p2 = {0.f, 0.f};
        #pragma unroll
        for (int m = 0; m < 4; ++m) {
            const float4 w4 = *reinterpret_cast<const float4*>(
                plds + 9 * 64 + m * 16 + kg4);
            const f32x2 alo = {acc3[m][0], acc3[m][1]};
            const f32x2 ahi = {acc3[m][2], acc3[m][3]};
            const f32x2 wlo = {w4.x, w4.y}, whi = {w4.z, w4.w};
            p2 = __builtin_elementwise_fma(alo, wlo, p2);
            p2 = __builtin_elementwise_fma(ahi, whi, p2);
        }
        float p = p2.x + p2.y;
        p += __shfl_xor(p, 16); p += __shfl_xor(p, 32);
        if (kg == 0) {
            const int e = (t << 4) + cl;
            if (e < E) {
                out[e] = __builtin_amdgcn_rcpf(
                    1.0f + __builtin_amdgcn_exp2f(p + b4s));
            }
        }
    }
}

__global__ __launch_bounds__(256) void cvt_x_bf16(const float* __restrict__ x,
                                                  unsigned short* __restrict__ xbf,
                                                  int n) {
    const int i = (blockIdx.x * 256 + threadIdx.x) * 8;
    if (i >= n) return;
    const float4 u0 = *reinterpret_cast<const float4*>(x + i);
    const float4 u1 = *reinterpret_cast<const float4*>(x + i + 4);
    uint4 t;
    t.x = pkbf(u0.x, u0.y); t.y = pkbf(u0.z, u0.w);
    t.z = pkbf(u1.x, u1.y); t.w = pkbf(u1.z, u1.w);
    *reinterpret_cast<uint4*>(xbf + i) = t;
}

extern "C" void kernel_launch(void* const* d_in, const int* in_sizes, int n_in,
                              void* d_out, int out_size, void* d_ws, size_t ws_size,
                              hipStream_t stream) {
    const float* x   = (const float*)d_in[0];
    const int*   ei  = (const int*)  d_in[1];
    const float* W1  = (const float*)d_in[2];
    const float* b1  = (const float*)d_in[3];
    const float* g1  = (const float*)d_in[4];
    const float* bt1 = (const float*)d_in[5];
    const float* W2  = (const float*)d_in[6];
    const float* b2  = (const float*)d_in[7];
    const float* g2  = (const float*)d_in[8];
    const float* bt2 = (const float*)d_in[9];
    const float* W3  = (const float*)d_in[10];
    const float* b3  = (const float*)d_in[11];
    const float* g3  = (const float*)d_in[12];
    const float* bt3 = (const float*)d_in[13];
    const float* W4  = (const float*)d_in[14];
    const float* b4  = (const float*)d_in[15];
    float* out = (float*)d_out;

    const int E  = in_sizes[1] / 2;
    const int nX = in_sizes[0];

    const bool prebf = (ws_size >= (size_t)nX * 2);

    if (prebf) {
        unsigned short* xbf = (unsigned short*)d_ws;
        const int grid_c = (nX / 8 + 255) / 256;
        hipLaunchKernelGGL(cvt_x_bf16, dim3(grid_c), dim3(256), 0, stream, x, xbf, nX);
        hipLaunchKernelGGL((edge_mlp_t<true>), dim3(GRID), dim3(BLOCK), 0, stream,
                           (const void*)xbf, ei, W1, b1, g1, bt1, W2, b2, g2, bt2,
                           W3, b3, g3, bt3, W4, b4, out, E);
    } else {
        hipLaunchKernelGGL((edge_mlp_t<false>), dim3(GRID), dim3(BLOCK), 0, stream,
                           (const void*)x, ei, W1, b1, g1, bt1, W2, b2, g2, bt2,
                           W3, b3, g3, bt3, W4, b4, out, E);
    }
}